// Round 2
// baseline (573.099 us; speedup 1.0000x reference)
//
#include <hip/hip_runtime.h>

typedef unsigned short u16;
typedef __attribute__((ext_vector_type(8))) __bf16 bf16x8;
typedef __attribute__((ext_vector_type(8))) short short8;
typedef __attribute__((ext_vector_type(4))) float f32x4;

#define TSEQ 2048
#define NBATCH 4
#define NHEAD 16
#define HDIM 64
#define CDIM 1024

__device__ __forceinline__ u16 f2bf(float f) {
  unsigned u = __float_as_uint(f);
  u += 0x7fffu + ((u >> 16) & 1u);   // round-to-nearest-even
  return (u16)(u >> 16);
}
__device__ __forceinline__ float bf2f(u16 s) {
  return __uint_as_float(((unsigned)s) << 16);
}

__device__ __forceinline__ f32x4 mfma_bf16(bf16x8 a, bf16x8 b, f32x4 c) {
  return __builtin_amdgcn_mfma_f32_16x16x32_bf16(a, b, c, 0, 0, 0);
}

// async global->LDS, 16B per lane. LDS dest is wave-uniform base + lane*16.
__device__ __forceinline__ void async16(const u16* g, u16* l) {
  __builtin_amdgcn_global_load_lds(
      (__attribute__((address_space(1))) unsigned int*)g,
      (__attribute__((address_space(3))) unsigned int*)l, 16, 0, 0);
}

// ---------------- fp32 -> bf16 convert ----------------
__global__ __launch_bounds__(256) void cvt_bf16(const float* __restrict__ in,
                                                u16* __restrict__ out, int n) {
  int i = (blockIdx.x * 256 + threadIdx.x) * 4;
  if (i >= n) return;
  float4 v = *reinterpret_cast<const float4*>(in + i);
  ushort4 o;
  o.x = f2bf(v.x); o.y = f2bf(v.y); o.z = f2bf(v.z); o.w = f2bf(v.w);
  *reinterpret_cast<ushort4*>(out + i) = o;
}

// ---------------- RoPE + RMSNorm (in place, bf16) ----------------
// one wave per (b,t,h) row of 64; lane = d
__global__ __launch_bounds__(256) void rope_rms(u16* __restrict__ qk,
                                                const float* __restrict__ cp,
                                                const float* __restrict__ sp) {
  int lane = threadIdx.x & 63;
  int rid = blockIdx.x * 4 + (threadIdx.x >> 6);   // (b*T + t)*H + h
  int t = (rid >> 4) & (TSEQ - 1);
  size_t off = (size_t)rid * HDIM + lane;
  float q = bf2f(qk[off]);
  float partner = __shfl_xor(q, 32);
  float rot = (lane < 32) ? -partner : partner;    // rotate_half
  float y = q * cp[t * HDIM + lane] + rot * sp[t * HDIM + lane];
  float ss = y * y;
  #pragma unroll
  for (int o = 1; o < 64; o <<= 1) ss += __shfl_xor(ss, o);
  float r = rsqrtf(ss * (1.0f / 64.0f) + 1e-6f);
  qk[off] = f2bf(y * r);
}

// ---------------- GEMM: C[m][n] = sum_k A[m][k] * Bt[n][k] ----------------
// 128x128 tile, BK=32, 256 threads = 4 waves (2x2), m97 structure.
template <bool OUT_F32>
__global__ __launch_bounds__(256) void gemm_bt(const u16* __restrict__ A,
                                               const u16* __restrict__ Bt,
                                               void* __restrict__ Cv,
                                               int M, int N, int K) {
  __shared__ __align__(16) u16 As[128 * 32];
  __shared__ __align__(16) u16 Bs[128 * 32];
  const int lane = threadIdx.x & 63;
  const int w = threadIdx.x >> 6;
  const int f = lane & 15, g = lane >> 4;
  const int wr = w >> 1, wc = w & 1;
  const size_t brow = (size_t)blockIdx.x * 128;
  const size_t bcol = (size_t)blockIdx.y * 128;
  const int ar = lane >> 2;          // row within 16-row chunk
  const int ac = (lane & 3) * 8;     // col (elements)
  f32x4 acc[4][4] = {};
  for (int k0 = 0; k0 < K; k0 += 32) {
    #pragma unroll
    for (int i = 0; i < 2; ++i) {
      const int c = w + i * 4;       // chunk 0..7 (16 rows each)
      async16(A + (brow + c * 16 + ar) * (size_t)K + (k0 + ac), &As[c * 512]);
      async16(Bt + (bcol + c * 16 + ar) * (size_t)K + (k0 + ac), &Bs[c * 512]);
    }
    __syncthreads();                 // drains vmcnt before barrier
    bf16x8 a[4], b[4];
    #pragma unroll
    for (int m = 0; m < 4; ++m)
      a[m] = *reinterpret_cast<const bf16x8*>(&As[(wr * 64 + m * 16 + f) * 32 + g * 8]);
    #pragma unroll
    for (int n = 0; n < 4; ++n)
      b[n] = *reinterpret_cast<const bf16x8*>(&Bs[(wc * 64 + n * 16 + f) * 32 + g * 8]);
    #pragma unroll
    for (int m = 0; m < 4; ++m)
      #pragma unroll
      for (int n = 0; n < 4; ++n)
        acc[m][n] = mfma_bf16(a[m], b[n], acc[m][n]);
    __syncthreads();
  }
  // epilogue: D row = (lane>>4)*4 + j, col = lane&15 (m89-verified layout)
  #pragma unroll
  for (int m = 0; m < 4; ++m)
    #pragma unroll
    for (int n = 0; n < 4; ++n)
      #pragma unroll
      for (int j = 0; j < 4; ++j) {
        size_t row = brow + wr * 64 + m * 16 + g * 4 + j;
        size_t col = bcol + wc * 64 + n * 16 + f;
        if constexpr (OUT_F32)
          reinterpret_cast<float*>(Cv)[row * (size_t)N + col] = acc[m][n][j];
        else
          reinterpret_cast<u16*>(Cv)[row * (size_t)N + col] = f2bf(acc[m][n][j]);
      }
}

// ---------------- flash attention ----------------
// grid (T/128, B*H), 256 threads = 4 waves; wave w owns q rows [128*bx + 32w, +32)
__global__ __launch_bounds__(256) void attn(const u16* __restrict__ Q,
                                            const u16* __restrict__ K,
                                            const u16* __restrict__ V,
                                            u16* __restrict__ Y) {
  __shared__ __align__(16) u16 P[4][32 * 128];   // per-wave P tile, XOR-swizzled
  const int lane = threadIdx.x & 63;
  const int w = threadIdx.x >> 6;
  const int f = lane & 15, g = lane >> 4;
  const int b = blockIdx.y >> 4, h = blockIdx.y & 15;
  const size_t base = ((size_t)b * TSEQ) * CDIM + h * HDIM;
  const int q0 = blockIdx.x * 128 + w * 32;
  u16* Pw = P[w];

  // Q A-frags hoisted to registers (contiguous 16B global loads)
  bf16x8 aq[2][2];
  #pragma unroll
  for (int mq = 0; mq < 2; ++mq)
    #pragma unroll
    for (int kq = 0; kq < 2; ++kq)
      aq[mq][kq] = *reinterpret_cast<const bf16x8*>(
          Q + base + (size_t)(q0 + mq * 16 + f) * CDIM + kq * 32 + g * 8);

  float mrun[2][4], lrun[2][4];
  f32x4 o[2][4] = {};
  #pragma unroll
  for (int mq = 0; mq < 2; ++mq)
    #pragma unroll
    for (int j = 0; j < 4; ++j) { mrun[mq][j] = -1e30f; lrun[mq][j] = 0.f; }

  for (int kt = 0; kt < TSEQ; kt += 128) {
    // ---- S = Q K^T (K B-frags straight from global/L2) ----
    f32x4 sa[2][8] = {};
    #pragma unroll
    for (int nf = 0; nf < 8; ++nf)
      #pragma unroll
      for (int kq = 0; kq < 2; ++kq) {
        bf16x8 bk = *reinterpret_cast<const bf16x8*>(
            K + base + (size_t)(kt + nf * 16 + f) * CDIM + kq * 32 + g * 8);
        sa[0][nf] = mfma_bf16(aq[0][kq], bk, sa[0][nf]);
        sa[1][nf] = mfma_bf16(aq[1][kq], bk, sa[1][nf]);
      }
    #pragma unroll
    for (int mq = 0; mq < 2; ++mq)
      #pragma unroll
      for (int nf = 0; nf < 8; ++nf)
        sa[mq][nf] *= 0.125f;   // 1/sqrt(D)

    // ---- online softmax (row = mq*16 + g*4 + j, col = nf*16 + f) ----
    float sf[2][4];
    #pragma unroll
    for (int mq = 0; mq < 2; ++mq)
      #pragma unroll
      for (int j = 0; j < 4; ++j) {
        float v = sa[mq][0][j];
        #pragma unroll
        for (int nf = 1; nf < 8; ++nf) v = fmaxf(v, sa[mq][nf][j]);
        #pragma unroll
        for (int off = 1; off < 16; off <<= 1) v = fmaxf(v, __shfl_xor(v, off));
        float mn = fmaxf(mrun[mq][j], v);
        sf[mq][j] = __expf(mrun[mq][j] - mn);
        mrun[mq][j] = mn;
      }
    float psum[2][4] = {};
    #pragma unroll
    for (int mq = 0; mq < 2; ++mq)
      #pragma unroll
      for (int nf = 0; nf < 8; ++nf)
        #pragma unroll
        for (int j = 0; j < 4; ++j) {
          float p = __expf(sa[mq][nf][j] - mrun[mq][j]);
          psum[mq][j] += p;
          int row = mq * 16 + g * 4 + j;
          int col = nf * 16 + f;
          Pw[row * 128 + (col ^ ((row & 7) << 3))] = f2bf(p);
        }
    #pragma unroll
    for (int mq = 0; mq < 2; ++mq)
      #pragma unroll
      for (int j = 0; j < 4; ++j) {
        float s = psum[mq][j];
        #pragma unroll
        for (int off = 1; off < 16; off <<= 1) s += __shfl_xor(s, off);
        lrun[mq][j] = lrun[mq][j] * sf[mq][j] + s;
      }
    #pragma unroll
    for (int mq = 0; mq < 2; ++mq)
      #pragma unroll
      for (int nfo = 0; nfo < 4; ++nfo)
        #pragma unroll
        for (int j = 0; j < 4; ++j) o[mq][nfo][j] *= sf[mq][j];

    // ---- O += P V  (P A-frags from per-wave LDS; V gathered from global) ----
    #pragma unroll
    for (int ks = 0; ks < 4; ++ks) {
      bf16x8 pa[2];
      #pragma unroll
      for (int mq = 0; mq < 2; ++mq) {
        int row = mq * 16 + f;
        pa[mq] = *reinterpret_cast<const bf16x8*>(
            &Pw[row * 128 + ((ks * 32 + g * 8) ^ ((row & 7) << 3))]);
      }
      #pragma unroll
      for (int nfo = 0; nfo < 4; ++nfo) {
        const u16* vp = V + base + (size_t)(kt + ks * 32 + g * 8) * CDIM + nfo * 16 + f;
        short8 bs;
        #pragma unroll
        for (int j = 0; j < 8; ++j) bs[j] = (short)vp[(size_t)j * CDIM];
        bf16x8 bv = __builtin_bit_cast(bf16x8, bs);
        o[0][nfo] = mfma_bf16(pa[0], bv, o[0][nfo]);
        o[1][nfo] = mfma_bf16(pa[1], bv, o[1][nfo]);
      }
    }
  }

  // ---- epilogue: Y = O / l ----
  #pragma unroll
  for (int mq = 0; mq < 2; ++mq)
    #pragma unroll
    for (int j = 0; j < 4; ++j) {
      float rcp = 1.0f / lrun[mq][j];
      #pragma unroll
      for (int nfo = 0; nfo < 4; ++nfo) {
        float val = o[mq][nfo][j] * rcp;
        Y[base + (size_t)(q0 + mq * 16 + g * 4 + j) * CDIM + nfo * 16 + f] = f2bf(val);
      }
    }
}

extern "C" void kernel_launch(void* const* d_in, const int* in_sizes, int n_in,
                              void* d_out, int out_size, void* d_ws, size_t ws_size,
                              hipStream_t stream) {
  const float* x  = (const float*)d_in[0];
  const float* cp = (const float*)d_in[1];
  const float* sp = (const float*)d_in[2];
  const float* Wq = (const float*)d_in[3];
  const float* Wk = (const float*)d_in[4];
  const float* Wv = (const float*)d_in[5];
  const float* Wo = (const float*)d_in[6];
  float* out = (float*)d_out;

  const int NX = NBATCH * TSEQ * CDIM;   // 8388608
  const int NW = CDIM * CDIM;            // 1048576

  // ws layout (needs 42 MB): xb/Yb | Vb | Wqb Wkb Wvb Wob
  u16* xb  = (u16*)d_ws;           // also reused as Y after QKV GEMMs
  u16* Vb  = xb + NX;
  u16* Wqb = Vb + NX;
  u16* Wkb = Wqb + NW;
  u16* Wvb = Wkb + NW;
  u16* Wob = Wvb + NW;
  // Q,K live in d_out (2 * 16.8MB bf16 == 33.6MB fp32) until the final GEMM
  u16* Qb = (u16*)d_out;
  u16* Kb = Qb + NX;

  cvt_bf16<<<NX / 1024, 256, 0, stream>>>(x, xb, NX);
  cvt_bf16<<<NW / 1024, 256, 0, stream>>>(Wq, Wqb, NW);
  cvt_bf16<<<NW / 1024, 256, 0, stream>>>(Wk, Wkb, NW);
  cvt_bf16<<<NW / 1024, 256, 0, stream>>>(Wv, Wvb, NW);
  cvt_bf16<<<NW / 1024, 256, 0, stream>>>(Wo, Wob, NW);

  dim3 gg(NBATCH * TSEQ / 128, CDIM / 128);   // (64, 8)
  gemm_bt<false><<<gg, 256, 0, stream>>>(xb, Wqb, Qb, NBATCH * TSEQ, CDIM, CDIM);
  gemm_bt<false><<<gg, 256, 0, stream>>>(xb, Wkb, Kb, NBATCH * TSEQ, CDIM, CDIM);
  gemm_bt<false><<<gg, 256, 0, stream>>>(xb, Wvb, Vb, NBATCH * TSEQ, CDIM, CDIM);

  rope_rms<<<NBATCH * TSEQ * NHEAD / 4, 256, 0, stream>>>(Qb, cp, sp);
  rope_rms<<<NBATCH * TSEQ * NHEAD / 4, 256, 0, stream>>>(Kb, cp, sp);

  dim3 ga(TSEQ / 128, NBATCH * NHEAD);        // (16, 64)
  attn<<<ga, 256, 0, stream>>>(Qb, Kb, Vb, xb);

  gemm_bt<true><<<gg, 256, 0, stream>>>(xb, Wob, out, NBATCH * TSEQ, CDIM, CDIM);
}